// Round 11
// baseline (180.136 us; speedup 1.0000x reference)
//
#include <hip/hip_runtime.h>
#include <hip/hip_bf16.h>

// Problem constants
#define BN   716      // nodes
#define BD   64       // feature dim
#define BH   4        // heads
#define BDH  16       // dim per head
#define BBS  48       // batch*seq
#define NCH  23       // j-chunks of 32 (23*32 = 736)
#define NJT  45       // j-tiles of 16 (45*16 = 720)
#define QSCALE 0.3606737602f   // 0.25 * log2(e): QK^T scores come out in log2 domain

typedef __hip_bfloat16 bf16;
typedef __attribute__((ext_vector_type(8))) short short8;
typedef __attribute__((ext_vector_type(4))) short s16x4;
typedef __attribute__((ext_vector_type(4))) float f32x4;

__device__ __forceinline__ float b2f(bf16 x){ return __bfloat162float(x); }
__device__ __forceinline__ bf16 f2b(float x){ return __float2bfloat16(x); }
__device__ __forceinline__ short bfbits(float x){
  union { bf16 h; short s; } c; c.h = __float2bfloat16(x); return c.s;
}
// pack two f32 -> two bf16 in one u32 (round-half-up via +0x8000, then v_perm)
__device__ __forceinline__ unsigned packbf(float a, float b){
  unsigned ua = __float_as_uint(a) + 0x8000u;
  unsigned ub = __float_as_uint(b) + 0x8000u;
  return __builtin_amdgcn_perm(ub, ua, 0x07060302u);  // low short=bf(a), high=bf(b)
}
__device__ __forceinline__ short8 pack8(float a,float b,float c,float d,
                                        float e,float f,float g,float h){
  short8 r; r[0]=bfbits(a); r[1]=bfbits(b); r[2]=bfbits(c); r[3]=bfbits(d);
  r[4]=bfbits(e); r[5]=bfbits(f); r[6]=bfbits(g); r[7]=bfbits(h); return r;
}
__device__ __forceinline__ float fexp2(float x){
#if __has_builtin(__builtin_amdgcn_exp2f)
  return __builtin_amdgcn_exp2f(x);
#else
  return __expf(x * 0.6931471805599453f);
#endif
}
__device__ __forceinline__ float frcp(float x){
#if __has_builtin(__builtin_amdgcn_rcpf)
  return __builtin_amdgcn_rcpf(x);
#else
  return 1.0f / x;
#endif
}

#define MFMA16(a,b,c) __builtin_amdgcn_mfma_f32_16x16x32_bf16(a,b,c,0,0,0)

#if __has_builtin(__builtin_amdgcn_mfma_f32_16x16x16_bf16)
#define HAVE_MFMA16K 1
__device__ __forceinline__ f32x4 mfma16k(s16x4 a, s16x4 b, f32x4 c){
  return __builtin_amdgcn_mfma_f32_16x16x16_bf16(a, b, c, 0, 0, 0);
}
#elif __has_builtin(__builtin_amdgcn_mfma_f32_16x16x16bf16_1k)
#define HAVE_MFMA16K 1
__device__ __forceinline__ f32x4 mfma16k(s16x4 a, s16x4 b, f32x4 c){
  return __builtin_amdgcn_mfma_f32_16x16x16bf16_1k(a, b, c, 0, 0, 0);
}
#else
#define HAVE_MFMA16K 0
#endif

// ---------------------------------------------------------------------------
// Kernel 0: parallel prep (mask / WB / WF / bfuse), 102 independent blocks.
__global__ __launch_bounds__(256) void k_prep(
    const int* __restrict__ adj,
    const float* __restrict__ W,  const float* __restrict__ Wq,
    const float* __restrict__ Wk, const float* __restrict__ Wv,
    const float* __restrict__ Wo, const float* __restrict__ bo,
    const float* __restrict__ Wp, const float* __restrict__ bp,
    unsigned* __restrict__ mask, bf16* __restrict__ WB,
    bf16* __restrict__ WF, float* __restrict__ bfuse)
{
  int b = blockIdx.x, t = threadIdx.x;
  if (b < 65){
    int w = b * 256 + t;
    if (w < BN * NCH){
      int row = w / NCH, wc = w - row * NCH;
      unsigned m = 0;
      int jb = wc * 32;
      for (int bb = 0; bb < 32; bb++){
        int j = jb + bb;
        if (j < BN && adj[(long)row * BN + j] > 0) m |= (1u << bb);
      }
      mask[w] = m;
    }
  } else if (b < 69){
#pragma unroll
    for (int i = 0; i < 16; i++){
      int idx = (b - 65) * 4096 + i * 256 + t;
      int n = idx >> 6, kk = idx & 63;
      const float* src = (n < 64) ? W : (n < 128) ? Wq : (n < 192) ? Wk : Wv;
      WB[idx] = f2b(src[kk * BD + (n & 63)]);
    }
  } else if (b < 101){
    int idx = (b - 69) * 256 + t;       // [0, 8192)
    int n = idx >> 7, kk = idx & 127;
    float v;
    if (kk < 64){
      v = Wp[kk * BD + n];
    } else {
      v = 0.f;
      int r = kk - 64;
      for (int m = 0; m < BD; m++)
        v += Wo[r * BD + m] * Wp[(BD + m) * BD + n];
    }
    WF[idx] = f2b(v);
  } else {
    if (t < BD){
      float acc = bp[t];
      for (int m = 0; m < BD; m++)
        acc += bo[m] * Wp[(BD + m) * BD + t];
      bfuse[t] = acc;
    }
  }
}

// ---------------------------------------------------------------------------
// Kernel 1: MFMA projections, single-barrier staging (4 LDS buffers).
//  WhS[bs][ch][d 64][k' 32]            (B-tiles, gat PV)
//  Vt16[bs][h][jt][lane 64][4]         (B-frags, mha PV, 16x16x16 order)
//  Qt/Kt[bs][h][jt][l15 16][k' 16]     (frags, mha QK^T; Qt scaled by 0.25*log2e)
//  Wh1[bs][n] fp32 ; EwP[bs][n] = (exp(Wh2), exp(0.2*Wh2)) fp32 pairs
__global__ __launch_bounds__(256) void k_proj(
    const float* __restrict__ x,
    const int* __restrict__ ind, const int* __restrict__ outd,
    const float* __restrict__ in_emb, const float* __restrict__ out_emb,
    const float* __restrict__ a1p, const float* __restrict__ a2p,
    const bf16* __restrict__ WB,
    const float* __restrict__ bq, const float* __restrict__ bk, const float* __restrict__ bv,
    bf16* __restrict__ WhS, float* __restrict__ Wh1, float2* __restrict__ EwP,
    bf16* __restrict__ Qt, bf16* __restrict__ Kt, bf16* __restrict__ Vt16)
{
  __shared__ short stA[64][72];   // Wh transposed [d][node]
  __shared__ short stB[64][72];   // V  transposed [d][node]
  __shared__ short stC[64][72];   // Q row-major [node][d]
  __shared__ short stD[64][72];   // K row-major [node][d]
  int bs = blockIdx.x, tile = blockIdx.y;
  int n0 = tile * 64;
  int t = threadIdx.x, w = t >> 6, lane = t & 63, quad = lane >> 4, l15 = lane & 15;
  long sb = (long)bs * BN;
  int rowi = n0 + w * 16 + l15;
  int rc = rowi < BN ? rowi : BN - 1;
  const float* xr  = x + (sb + rc) * BD;
  const float* ier = in_emb  + (long)ind [rc] * BD;
  const float* oer = out_emb + (long)outd[rc] * BD;

  f32x4 aw[4], aqkv[12];
#pragma unroll
  for (int i2 = 0; i2 < 4;  i2++) aw[i2]   = (f32x4){0,0,0,0};
#pragma unroll
  for (int i2 = 0; i2 < 12; i2++) aqkv[i2] = (f32x4){0,0,0,0};

#pragma unroll
  for (int kc = 0; kc < 2; kc++){
    int k0 = kc * 32 + quad * 8;
    float4 xa = *(const float4*)(xr  + k0);
    float4 xb = *(const float4*)(xr  + k0 + 4);
    float4 ia = *(const float4*)(ier + k0);
    float4 ib = *(const float4*)(ier + k0 + 4);
    float4 oa = *(const float4*)(oer + k0);
    float4 ob = *(const float4*)(oer + k0 + 4);
    short8 ax = pack8(xa.x, xa.y, xa.z, xa.w, xb.x, xb.y, xb.z, xb.w);
    short8 ay = pack8(xa.x+ia.x+oa.x, xa.y+ia.y+oa.y, xa.z+ia.z+oa.z, xa.w+ia.w+oa.w,
                      xb.x+ib.x+ob.x, xb.y+ib.y+ob.y, xb.z+ib.z+ob.z, xb.w+ib.w+ob.w);
#pragma unroll
    for (int nt = 0; nt < 4; nt++)
      aw[nt] = MFMA16(ax, *(const short8*)(WB + (nt*16 + l15) * BD + k0), aw[nt]);
#pragma unroll
    for (int nt = 0; nt < 12; nt++)
      aqkv[nt] = MFMA16(ay, *(const short8*)(WB + (64 + nt*16 + l15) * BD + k0), aqkv[nt]);
  }

  // Wh1 + exp-factor table from fp32 C-frags
  {
    float s1v[4] = {0,0,0,0}, s2v[4] = {0,0,0,0};
#pragma unroll
    for (int nt = 0; nt < 4; nt++){
      float a1f = a1p[nt*16 + l15], a2f = a2p[nt*16 + l15];
#pragma unroll
      for (int reg = 0; reg < 4; reg++){
        s1v[reg] += aw[nt][reg] * a1f;
        s2v[reg] += aw[nt][reg] * a2f;
      }
    }
#pragma unroll
    for (int off = 1; off < 16; off <<= 1){
#pragma unroll
      for (int reg = 0; reg < 4; reg++){
        s1v[reg] += __shfl_xor(s1v[reg], off);
        s2v[reg] += __shfl_xor(s2v[reg], off);
      }
    }
    if (l15 == 0){
#pragma unroll
      for (int reg = 0; reg < 4; reg++){
        int rr = n0 + w*16 + quad*4 + reg;
        if (rr < BN){
          Wh1[sb + rr] = s1v[reg];
          float s2 = s2v[reg];
          EwP[sb + rr] = make_float2(__expf(s2), __expf(0.2f * s2));
        }
      }
    }
  }

  // ---- write ALL four staging buffers, then ONE barrier ----
#pragma unroll
  for (int nt = 0; nt < 4; nt++){
    *(short4*)&stA[nt*16 + l15][w*16 + quad*4] = make_short4(
        bfbits(aw[nt][0]), bfbits(aw[nt][1]), bfbits(aw[nt][2]), bfbits(aw[nt][3]));
    float bb = bv[nt*16 + l15];
    *(short4*)&stB[nt*16 + l15][w*16 + quad*4] = make_short4(
        bfbits(aqkv[8+nt][0]+bb), bfbits(aqkv[8+nt][1]+bb),
        bfbits(aqkv[8+nt][2]+bb), bfbits(aqkv[8+nt][3]+bb));
    float bq_ = bq[nt*16 + l15];
    float bk_ = bk[nt*16 + l15];
#pragma unroll
    for (int reg = 0; reg < 4; reg++){
      stC[w*16 + quad*4 + reg][nt*16 + l15] = bfbits((aqkv[nt][reg] + bq_) * QSCALE);
      stD[w*16 + quad*4 + reg][nt*16 + l15] = bfbits(aqkv[4+nt][reg] + bk_);
    }
  }
  __syncthreads();

  // ---- WhS from stA ----
#pragma unroll
  for (int s = 0; s < 2; s++){
    int L = (t*2 + s) * 8;
    int kb = L & 31, d = (L >> 5) & 63, chl = L >> 11;
    int ch = tile * 2 + chl;
    if (ch < NCH)
      *(uint4*)(WhS + (((long)bs*NCH + ch)*64 + d)*32 + kb) = *(const uint4*)&stA[d][chl*32 + kb];
  }
  // ---- Vt16 from stB ----
  {
    int jl = t >> 6;               // 4 local jt tiles
    int c  = t & 15, qq = (t >> 4) & 3;
    int jt = tile * 4 + jl;
    if (jt < NJT){
#pragma unroll
      for (int h = 0; h < BH; h++){
        s16x4 v4 = *(const s16x4*)&stB[h*16 + c][jl*16 + qq*4];
        *(s16x4*)(Vt16 + ((((long)bs*BH + h)*NJT + jt)*64 + (t & 63))*4) = v4;
      }
    }
  }
  // ---- Qt from stC, Kt from stD ----
#pragma unroll
  for (int s = 0; s < 2; s++){
    int L = (t*2 + s) * 8;
    int kb = L & 15, nl = (L >> 4) & 63, h = L >> 10;
    int jt = tile * 4 + (nl >> 4);
    if (jt < NJT){
      *(uint4*)(Qt + ((((long)bs*BH + h)*NJT + jt)*16 + (nl&15))*16 + kb)
          = *(const uint4*)&stC[nl][h*16 + kb];
      *(uint4*)(Kt + ((((long)bs*BH + h)*NJT + jt)*16 + (nl&15))*16 + kb)
          = *(const uint4*)&stD[nl][h*16 + kb];
    }
  }
}

// ---------------------------------------------------------------------------
// Kernel 2: merged attention. Grid (bs, 57):
//  y in [0,12):  GAT — wave = 16-row tile rt = y*4+w (no LDS, no barriers)
//  y in [12,57): MHA — wave = head, one q-tile rt = y-12, K=16 MFMA throughout
__global__ __launch_bounds__(256) void k_attn(
    const float* __restrict__ Wh1, const float2* __restrict__ EwP,
    const unsigned* __restrict__ mask, const bf16* __restrict__ WhS,
    const bf16* __restrict__ Qt, const bf16* __restrict__ Kt,
    const bf16* __restrict__ Vt16,
    bf16* __restrict__ out1, bf16* __restrict__ o)
{
#if !HAVE_MFMA16K
  __shared__ short pw[4][16][48];
#endif
  int bs = blockIdx.x, yb = blockIdx.y;
  int t = threadIdx.x, w = t >> 6, lane = t & 63, quad = lane >> 4, l15 = lane & 15;
  long sb = (long)bs * BN;

  if (yb < 12){
    // ======================= GAT path (factorized exp) =======================
    int rt = yb * 4 + w;
    if (rt >= NJT) return;
    int i = rt * 16 + l15;
    int ic = i < BN ? i : BN - 1;
    float e1 = Wh1[sb + ic];
    float Aa = __expf(e1), Cc = __expf(0.2f * e1);
    float invA = frcp(Aa);               // cond: e1+w2>0  <=>  exp(w2) > 1/exp(e1)
    const unsigned* mrow = mask + (long)ic * NCH;
    const float2* ew = EwP + sb;

    float sl = 0.f;
    f32x4 acc0 = {0,0,0,0}, acc1 = {0,0,0,0}, acc2 = {0,0,0,0}, acc3 = {0,0,0,0};
    for (int ch = 0; ch < NCH; ch++){
      int j0 = ch * 32 + quad * 8;
      unsigned m8 = (mrow[ch] >> (quad * 8)) & 0xFFu;
      const float4* ef = (const float4*)(ew + j0);  // OOB tail: finite, masked
      float4 q0 = ef[0], q1 = ef[1], q2 = ef[2], q3 = ef[3];
      float Bv[8] = {q0.x, q0.z, q1.x, q1.z, q2.x, q2.z, q3.x, q3.z};
      float Dv[8] = {q0.y, q0.w, q1.y, q1.w, q2.y, q2.w, q3.y, q3.w};
      float p[8];
#pragma unroll
      for (int jj = 0; jj < 8; jj++){
        bool cond = Bv[jj] > invA;
        float f = cond ? Bv[jj] : Dv[jj];
        float g = cond ? Aa : Cc;
        float pp = ((m8 >> jj) & 1u) ? f * g : 0.f;
        sl += pp;
        p[jj] = pp;
      }
      union { unsigned u[4]; short8 v; } A;
      A.u[0] = packbf(p[0], p[1]); A.u[1] = packbf(p[2], p[3]);
      A.u[2] = packbf(p[4], p[5]); A.u[3] = packbf(p[6], p[7]);
      const bf16* wbp = WhS + ((long)bs*NCH + ch)*2048 + quad * 8;
      acc0 = MFMA16(A.v, *(const short8*)(wbp + ( 0 + l15) * 32), acc0);
      acc1 = MFMA16(A.v, *(const short8*)(wbp + (16 + l15) * 32), acc1);
      acc2 = MFMA16(A.v, *(const short8*)(wbp + (32 + l15) * 32), acc2);
      acc3 = MFMA16(A.v, *(const short8*)(wbp + (48 + l15) * 32), acc3);
    }
    sl += __shfl_xor(sl, 16);
    sl += __shfl_xor(sl, 32);
    float inv[4];
#pragma unroll
    for (int reg = 0; reg < 4; reg++){
      int srcl = quad * 4 + reg;
      float s = __int_as_float(__builtin_amdgcn_ds_bpermute(srcl << 2, __float_as_int(sl)));
      inv[reg] = 1.0f / s;
    }
    const f32x4* accs[4] = {&acc0, &acc1, &acc2, &acc3};
#pragma unroll
    for (int nt = 0; nt < 4; nt++){
#pragma unroll
      for (int reg = 0; reg < 4; reg++){
        int gi = rt * 16 + quad * 4 + reg;
        if (gi < BN){
          float val = (*accs[nt])[reg] * inv[reg];
          val = (val > 0.f) ? val : (__expf(val) - 1.f);   // ELU
          out1[(sb + gi) * BD + nt*16 + l15] = f2b(val);
        }
      }
    }
    return;
  }

  // ======================= MHA path (K=16 MFMA, 1 q-tile) =======================
  int h = w, rt = yb - 12;
  const bf16* Qh = Qt   + ((long)bs*BH + h) * NJT * 256;
  const bf16* Kh = Kt   + ((long)bs*BH + h) * NJT * 256;
  const bf16* Vh = Vt16 + ((long)bs*BH + h) * NJT * 256;

  f32x4 oacc = {0,0,0,0};
  float psum = 0.f;

#if HAVE_MFMA16K
  s16x4 bq16 = *(const s16x4*)(Qh + rt*256 + l15*16 + quad*4);  // B: Q[q=l15][k=quad*4+i]
#pragma unroll 4
  for (int jt = 0; jt < NJT - 1; jt++){
    s16x4 ak = *(const s16x4*)(Kh + jt*256 + l15*16 + quad*4);  // A: K[j=l15][k]
    f32x4 c = mfma16k(ak, bq16, ((f32x4){0,0,0,0}));            // S^T (log2 domain)
    float p[4];
#pragma unroll
    for (int reg = 0; reg < 4; reg++){
      float pp = fexp2(c[reg]);
      psum += pp;
      p[reg] = pp;
    }
    union { unsigned u[2]; s16x4 v; } A;
    A.u[0] = packbf(p[0], p[1]); A.u[1] = packbf(p[2], p[3]);
    s16x4 bv = *(const s16x4*)(Vh + jt*256 + lane*4);
    oacc = mfma16k(A.v, bv, oacc);
  }
  { // tail jt = 44: zero j >= 716 (quad 3 rows of S^T)
    int jt = NJT - 1;
    s16x4 ak = *(const s16x4*)(Kh + jt*256 + l15*16 + quad*4);
    f32x4 c = mfma16k(ak, bq16, ((f32x4){0,0,0,0}));
    float p[4];
#pragma unroll
    for (int reg = 0; reg < 4; reg++){
      float pp = (quad == 3) ? 0.f : fexp2(c[reg]);
      psum += pp;
      p[reg] = pp;
    }
    union { unsigned u[2]; s16x4 v; } A;
    A.u[0] = packbf(p[0], p[1]); A.u[1] = packbf(p[2], p[3]);
    s16x4 bv = *(const s16x4*)(Vh + jt*256 + lane*4);
    oacc = mfma16k(A.v, bv, oacc);
  }
#else
  short8 aq = {0,0,0,0,0,0,0,0};
  if (quad < 2) aq = *(const short8*)(Qh + rt*256 + l15*16 + quad*8);
  for (int ch = 0; ch < NCH; ch++){
#pragma unroll
    for (int tt = 0; tt < 2; tt++){
      int jt = 2*ch + tt;
      if (jt < NJT){
        short8 ak = {0,0,0,0,0,0,0,0};
        if (quad < 2) ak = *(const short8*)(Kh + jt*256 + l15*16 + quad*8);
        f32x4 c = MFMA16(ak, aq, ((f32x4){0,0,0,0}));
        bool inval = (jt == NJT-1) && (quad == 3);
#pragma unroll
        for (int reg = 0; reg < 4; reg++){
          float pp = fexp2(c[reg]);
          pp = inval ? 0.f : pp;
          psum += pp;
          pw[h][l15][tt*16 + quad*4 + reg] = (short)((__float_as_uint(pp) + 0x8000u) >> 16);
        }
      } else {
#pragma unroll
        for (int reg = 0; reg < 4; reg++) pw[h][l15][tt*16 + quad*4 + reg] = 0;
      }
    }
    short8 ap = *(const short8*)&pw[h][l15][quad*8];
    int jB = 2*ch + (quad >> 1);
    s16x4 v0 = {0,0,0,0}, v1 = {0,0,0,0};
    if (jB < NJT){
      v0 = *(const s16x4*)(Vh + jB*256 + (((quad&1)*2  )*16 + l15)*4);
      v1 = *(const s16x4*)(Vh + jB*256 + (((quad&1)*2+1)*16 + l15)*4);
    }
    short8 bv8; bv8[0]=v0[0]; bv8[1]=v0[1]; bv8[2]=v0[2]; bv8[3]=v0[3];
    bv8[4]=v1[0]; bv8[5]=v1[1]; bv8[6]=v1[2]; bv8[7]=v1[3];
    oacc = MFMA16(ap, bv8, oacc);
  }
#endif

  psum += __shfl_xor(psum, 16);
  psum += __shfl_xor(psum, 32);
#pragma unroll
  for (int reg = 0; reg < 4; reg++){
    int srcl = quad * 4 + reg;
    float s = __int_as_float(__builtin_amdgcn_ds_bpermute(srcl << 2, __float_as_int(psum)));
    int grow = rt * 16 + srcl;
    if (grow < BN)
      o[(sb + grow) * BD + h * BDH + l15] = f2b(oacc[reg] / s);
  }
}

// ---------------------------------------------------------------------------
// Kernel 3: MFMA epilogue: out = [out1|o] @ WF^T + bfuse.
__global__ __launch_bounds__(256) void k_final(
    const bf16* __restrict__ out1, const bf16* __restrict__ o,
    const bf16* __restrict__ WF, const float* __restrict__ bfuse,
    float* __restrict__ out)
{
  int t = threadIdx.x, w = t >> 6, lane = t & 63, quad = lane >> 4, l15 = lane & 15;
  long r0 = (long)blockIdx.x * 64;
  long row = r0 + w * 16 + l15;
  const bf16* o1r = out1 + row * BD;
  const bf16* oor = o    + row * BD;
  f32x4 acc[4];
#pragma unroll
  for (int i2 = 0; i2 < 4; i2++) acc[i2] = (f32x4){0,0,0,0};
#pragma unroll
  for (int kc = 0; kc < 2; kc++){
    int k0 = kc * 32 + quad * 8;
    short8 a1 = *(const short8*)(o1r + k0);
    short8 a2 = *(const short8*)(oor + k0);
#pragma unroll
    for (int nt = 0; nt < 4; nt++){
      acc[nt] = MFMA16(a1, *(const short8*)(WF + (nt*16 + l15) * 128 + k0), acc[nt]);
      acc[nt] = MFMA16(a2, *(const short8*)(WF + (nt*16 + l15) * 128 + 64 + k0), acc[nt]);
    }
  }
#pragma unroll
  for (int nt = 0; nt < 4; nt++){
    float bf = bfuse[nt*16 + l15];
#pragma unroll
    for (int reg = 0; reg < 4; reg++)
      out[(r0 + w*16 + quad*4 + reg) * BD + nt*16 + l15] = acc[nt][reg] + bf;
  }
}

// ---------------------------------------------------------------------------
extern "C" void kernel_launch(void* const* d_in, const int* in_sizes, int n_in,
                              void* d_out, int out_size, void* d_ws, size_t ws_size,
                              hipStream_t stream){
  const float* inp    = (const float*)d_in[0];
  const int*   adj    = (const int*)  d_in[1];
  const int*   ind    = (const int*)  d_in[2];
  const int*   outd   = (const int*)  d_in[3];
  const float* in_emb = (const float*)d_in[4];
  const float* out_emb= (const float*)d_in[5];
  const float* W      = (const float*)d_in[6];
  const float* a1     = (const float*)d_in[7];
  const float* a2     = (const float*)d_in[8];
  const float* Wq     = (const float*)d_in[9];
  const float* bq     = (const float*)d_in[10];
  const float* Wk     = (const float*)d_in[11];
  const float* bk     = (const float*)d_in[12];
  const float* Wv     = (const float*)d_in[13];
  const float* bv     = (const float*)d_in[14];
  const float* Wo     = (const float*)d_in[15];
  const float* bo     = (const float*)d_in[16];
  const float* Wp     = (const float*)d_in[17];
  const float* bp     = (const float*)d_in[18];

  const long PER  = (long)BBS * BN * BD;             // 2,199,552
  const long WHS  = (long)BBS * NCH * 64 * 32;       // 2,260,992
  const long QTS  = (long)BBS * BH * NJT * 16 * 16;  // 2,211,840
  bf16* WhSb  = (bf16*)d_ws;
  bf16* Vt16b = WhSb  + WHS;
  bf16* Qtb   = Vt16b + QTS;
  bf16* Ktb   = Qtb   + QTS;
  bf16* o1B   = Ktb   + QTS;
  bf16* oB    = o1B + PER;            // dedicated (GAT/MHA blocks run concurrently)
  bf16* WBb   = oB  + PER;            // 256*64
  bf16* WFb   = WBb + 256 * BD;       // 64*128
  unsigned* maskb = (unsigned*)(WFb + BD * 128);     // 716*23 words (65872 B, 16B-aligned)
  float2* EwPb = (float2*)(maskb + BN * NCH);        // BBS*BN pairs + 32 pad
  float* fws  = (float*)(EwPb + (long)BBS * BN + 32);
  float* Wh1  = fws;
  float* bfuse= Wh1 + (long)BBS * BN + 64;
  // total ~= 27.3 MiB (ws_size = 256 MiB per harness poison-fill size)

  hipLaunchKernelGGL(k_prep, dim3(102), dim3(256), 0, stream,
                     adj, W, Wq, Wk, Wv, Wo, bo, Wp, bp,
                     maskb, WBb, WFb, bfuse);
  hipLaunchKernelGGL(k_proj, dim3(BBS, 12), dim3(256), 0, stream,
                     inp, ind, outd, in_emb, out_emb, a1, a2, WBb, bq, bk, bv,
                     WhSb, Wh1, EwPb, Qtb, Ktb, Vt16b);
  hipLaunchKernelGGL(k_attn, dim3(BBS, 57), dim3(256), 0, stream,
                     Wh1, EwPb, maskb, WhSb, Qtb, Ktb, Vt16b, o1B, oB);
  hipLaunchKernelGGL(k_final, dim3(537), dim3(256), 0, stream,
                     o1B, oB, WFb, bfuse, (float*)d_out);
}

// Round 12
// 173.566 us; speedup vs baseline: 1.0379x; 1.0379x over previous
//
#include <hip/hip_runtime.h>
#include <hip/hip_bf16.h>

// Problem constants
#define BN   716      // nodes
#define BD   64       // feature dim
#define BH   4        // heads
#define BDH  16       // dim per head
#define BBS  48       // batch*seq
#define NCH  23       // j-chunks of 32 (23*32 = 736)
#define NJT  45       // j-tiles of 16 (45*16 = 720)
#define NJP  22       // jt pairs (44 = 22*2), jt=44 is the tail
#define KVSZ 11520    // per (bs,h) elements of Ktp/Vtp/Qt (45*256)
#define KVTAIL 11264  // offset of tail jt=44 region (22*512)
#define QSCALE 0.3606737602f   // 0.25 * log2(e): QK^T scores come out in log2 domain

typedef __hip_bfloat16 bf16;
typedef __attribute__((ext_vector_type(8))) short short8;
typedef __attribute__((ext_vector_type(4))) short s16x4;
typedef __attribute__((ext_vector_type(4))) float f32x4;

__device__ __forceinline__ float b2f(bf16 x){ return __bfloat162float(x); }
__device__ __forceinline__ bf16 f2b(float x){ return __float2bfloat16(x); }
__device__ __forceinline__ short bfbits(float x){
  union { bf16 h; short s; } c; c.h = __float2bfloat16(x); return c.s;
}
// pack two f32 -> two bf16 in one u32 (round-half-up via +0x8000, then v_perm)
__device__ __forceinline__ unsigned packbf(float a, float b){
  unsigned ua = __float_as_uint(a) + 0x8000u;
  unsigned ub = __float_as_uint(b) + 0x8000u;
  return __builtin_amdgcn_perm(ub, ua, 0x07060302u);  // low short=bf(a), high=bf(b)
}
__device__ __forceinline__ short8 pack8(float a,float b,float c,float d,
                                        float e,float f,float g,float h){
  short8 r; r[0]=bfbits(a); r[1]=bfbits(b); r[2]=bfbits(c); r[3]=bfbits(d);
  r[4]=bfbits(e); r[5]=bfbits(f); r[6]=bfbits(g); r[7]=bfbits(h); return r;
}
__device__ __forceinline__ float fexp2(float x){
#if __has_builtin(__builtin_amdgcn_exp2f)
  return __builtin_amdgcn_exp2f(x);
#else
  return __expf(x * 0.6931471805599453f);
#endif
}
__device__ __forceinline__ float frcp(float x){
#if __has_builtin(__builtin_amdgcn_rcpf)
  return __builtin_amdgcn_rcpf(x);
#else
  return 1.0f / x;
#endif
}

#define MFMA16(a,b,c) __builtin_amdgcn_mfma_f32_16x16x32_bf16(a,b,c,0,0,0)

#if __has_builtin(__builtin_amdgcn_mfma_f32_16x16x16_bf16)
#define HAVE_MFMA16K 1
__device__ __forceinline__ f32x4 mfma16k(s16x4 a, s16x4 b, f32x4 c){
  return __builtin_amdgcn_mfma_f32_16x16x16_bf16(a, b, c, 0, 0, 0);
}
#elif __has_builtin(__builtin_amdgcn_mfma_f32_16x16x16bf16_1k)
#define HAVE_MFMA16K 1
__device__ __forceinline__ f32x4 mfma16k(s16x4 a, s16x4 b, f32x4 c){
  return __builtin_amdgcn_mfma_f32_16x16x16bf16_1k(a, b, c, 0, 0, 0);
}
#else
#define HAVE_MFMA16K 0
#endif

// ---------------------------------------------------------------------------
// Kernel 0: parallel prep (mask / WB / WF / bfuse), 102 independent blocks.
__global__ __launch_bounds__(256) void k_prep(
    const int* __restrict__ adj,
    const float* __restrict__ W,  const float* __restrict__ Wq,
    const float* __restrict__ Wk, const float* __restrict__ Wv,
    const float* __restrict__ Wo, const float* __restrict__ bo,
    const float* __restrict__ Wp, const float* __restrict__ bp,
    unsigned* __restrict__ mask, bf16* __restrict__ WB,
    bf16* __restrict__ WF, float* __restrict__ bfuse)
{
  int b = blockIdx.x, t = threadIdx.x;
  if (b < 65){
    int w = b * 256 + t;
    if (w < BN * NCH){
      int row = w / NCH, wc = w - row * NCH;
      unsigned m = 0;
      int jb = wc * 32;
      for (int bb = 0; bb < 32; bb++){
        int j = jb + bb;
        if (j < BN && adj[(long)row * BN + j] > 0) m |= (1u << bb);
      }
      mask[w] = m;
    }
  } else if (b < 69){
#pragma unroll
    for (int i = 0; i < 16; i++){
      int idx = (b - 65) * 4096 + i * 256 + t;
      int n = idx >> 6, kk = idx & 63;
      const float* src = (n < 64) ? W : (n < 128) ? Wq : (n < 192) ? Wk : Wv;
      WB[idx] = f2b(src[kk * BD + (n & 63)]);
    }
  } else if (b < 101){
    int idx = (b - 69) * 256 + t;       // [0, 8192)
    int n = idx >> 7, kk = idx & 127;
    float v;
    if (kk < 64){
      v = Wp[kk * BD + n];
    } else {
      v = 0.f;
      int r = kk - 64;
      for (int m = 0; m < BD; m++)
        v += Wo[r * BD + m] * Wp[(BD + m) * BD + n];
    }
    WF[idx] = f2b(v);
  } else {
    if (t < BD){
      float acc = bp[t];
      for (int m = 0; m < BD; m++)
        acc += bo[m] * Wp[(BD + m) * BD + t];
      bfuse[t] = acc;
    }
  }
}

// ---------------------------------------------------------------------------
// Kernel 1: MFMA projections, single-barrier staging (4 LDS buffers).
//  WhS[bs][ch][d 64][k' 32]                 (B-tiles, gat PV)
//  Vtp[bs][h]: jt-pair interleaved PV frags  (pairs [jp][lane][tl][4], tail at 11264)
//  Ktp[bs][h]: jt-pair interleaved QK frags  (pairs [jp][l15][kq][tl][4], tail)
//  Qt [bs][h][jt][l15 16][k' 16]            (scaled by 0.25*log2e)
//  Wh1[bs][n] fp32 ; EwP[bs][n] = (exp(Wh2), exp(0.2*Wh2)) fp32 pairs
__global__ __launch_bounds__(256) void k_proj(
    const float* __restrict__ x,
    const int* __restrict__ ind, const int* __restrict__ outd,
    const float* __restrict__ in_emb, const float* __restrict__ out_emb,
    const float* __restrict__ a1p, const float* __restrict__ a2p,
    const bf16* __restrict__ WB,
    const float* __restrict__ bq, const float* __restrict__ bk, const float* __restrict__ bv,
    bf16* __restrict__ WhS, float* __restrict__ Wh1, float2* __restrict__ EwP,
    bf16* __restrict__ Qt, bf16* __restrict__ Ktp, bf16* __restrict__ Vtp)
{
  __shared__ short stA[64][72];   // Wh transposed [d][node]
  __shared__ short stB[64][72];   // V  transposed [d][node]
  __shared__ short stC[64][72];   // Q row-major [node][d]
  __shared__ short stD[64][72];   // K row-major [node][d]
  int bs = blockIdx.x, tile = blockIdx.y;
  int n0 = tile * 64;
  int t = threadIdx.x, w = t >> 6, lane = t & 63, quad = lane >> 4, l15 = lane & 15;
  long sb = (long)bs * BN;
  int rowi = n0 + w * 16 + l15;
  int rc = rowi < BN ? rowi : BN - 1;
  const float* xr  = x + (sb + rc) * BD;
  const float* ier = in_emb  + (long)ind [rc] * BD;
  const float* oer = out_emb + (long)outd[rc] * BD;

  f32x4 aw[4], aqkv[12];
#pragma unroll
  for (int i2 = 0; i2 < 4;  i2++) aw[i2]   = (f32x4){0,0,0,0};
#pragma unroll
  for (int i2 = 0; i2 < 12; i2++) aqkv[i2] = (f32x4){0,0,0,0};

#pragma unroll
  for (int kc = 0; kc < 2; kc++){
    int k0 = kc * 32 + quad * 8;
    float4 xa = *(const float4*)(xr  + k0);
    float4 xb = *(const float4*)(xr  + k0 + 4);
    float4 ia = *(const float4*)(ier + k0);
    float4 ib = *(const float4*)(ier + k0 + 4);
    float4 oa = *(const float4*)(oer + k0);
    float4 ob = *(const float4*)(oer + k0 + 4);
    short8 ax = pack8(xa.x, xa.y, xa.z, xa.w, xb.x, xb.y, xb.z, xb.w);
    short8 ay = pack8(xa.x+ia.x+oa.x, xa.y+ia.y+oa.y, xa.z+ia.z+oa.z, xa.w+ia.w+oa.w,
                      xb.x+ib.x+ob.x, xb.y+ib.y+ob.y, xb.z+ib.z+ob.z, xb.w+ib.w+ob.w);
#pragma unroll
    for (int nt = 0; nt < 4; nt++)
      aw[nt] = MFMA16(ax, *(const short8*)(WB + (nt*16 + l15) * BD + k0), aw[nt]);
#pragma unroll
    for (int nt = 0; nt < 12; nt++)
      aqkv[nt] = MFMA16(ay, *(const short8*)(WB + (64 + nt*16 + l15) * BD + k0), aqkv[nt]);
  }

  // Wh1 + exp-factor table from fp32 C-frags
  {
    float s1v[4] = {0,0,0,0}, s2v[4] = {0,0,0,0};
#pragma unroll
    for (int nt = 0; nt < 4; nt++){
      float a1f = a1p[nt*16 + l15], a2f = a2p[nt*16 + l15];
#pragma unroll
      for (int reg = 0; reg < 4; reg++){
        s1v[reg] += aw[nt][reg] * a1f;
        s2v[reg] += aw[nt][reg] * a2f;
      }
    }
#pragma unroll
    for (int off = 1; off < 16; off <<= 1){
#pragma unroll
      for (int reg = 0; reg < 4; reg++){
        s1v[reg] += __shfl_xor(s1v[reg], off);
        s2v[reg] += __shfl_xor(s2v[reg], off);
      }
    }
    if (l15 == 0){
#pragma unroll
      for (int reg = 0; reg < 4; reg++){
        int rr = n0 + w*16 + quad*4 + reg;
        if (rr < BN){
          Wh1[sb + rr] = s1v[reg];
          float s2 = s2v[reg];
          EwP[sb + rr] = make_float2(__expf(s2), __expf(0.2f * s2));
        }
      }
    }
  }

  // ---- write ALL four staging buffers, then ONE barrier ----
#pragma unroll
  for (int nt = 0; nt < 4; nt++){
    *(short4*)&stA[nt*16 + l15][w*16 + quad*4] = make_short4(
        bfbits(aw[nt][0]), bfbits(aw[nt][1]), bfbits(aw[nt][2]), bfbits(aw[nt][3]));
    float bb = bv[nt*16 + l15];
    *(short4*)&stB[nt*16 + l15][w*16 + quad*4] = make_short4(
        bfbits(aqkv[8+nt][0]+bb), bfbits(aqkv[8+nt][1]+bb),
        bfbits(aqkv[8+nt][2]+bb), bfbits(aqkv[8+nt][3]+bb));
    float bq_ = bq[nt*16 + l15];
    float bk_ = bk[nt*16 + l15];
#pragma unroll
    for (int reg = 0; reg < 4; reg++){
      stC[w*16 + quad*4 + reg][nt*16 + l15] = bfbits((aqkv[nt][reg] + bq_) * QSCALE);
      stD[w*16 + quad*4 + reg][nt*16 + l15] = bfbits(aqkv[4+nt][reg] + bk_);
    }
  }
  __syncthreads();

  // ---- WhS from stA ----
#pragma unroll
  for (int s = 0; s < 2; s++){
    int L = (t*2 + s) * 8;
    int kb = L & 31, d = (L >> 5) & 63, chl = L >> 11;
    int ch = tile * 2 + chl;
    if (ch < NCH)
      *(uint4*)(WhS + (((long)bs*NCH + ch)*64 + d)*32 + kb) = *(const uint4*)&stA[d][chl*32 + kb];
  }
  // ---- Vtp from stB (pair-interleaved) ----
  {
    int jl = t >> 6;               // 4 local jt tiles
    int c  = t & 15, qq = (t >> 4) & 3;
    int jt = tile * 4 + jl;
    int L  = t & 63;
    if (jt < NJT){
#pragma unroll
      for (int h = 0; h < BH; h++){
        s16x4 v4 = *(const s16x4*)&stB[h*16 + c][jl*16 + qq*4];
        long base = ((long)bs*BH + h) * KVSZ;
        if (jt < 44)
          *(s16x4*)(Vtp + base + (jt>>1)*512 + L*8 + (jt&1)*4) = v4;
        else
          *(s16x4*)(Vtp + base + KVTAIL + L*4) = v4;
      }
    }
  }
  // ---- Qt from stC, Ktp from stD ----
#pragma unroll
  for (int s = 0; s < 2; s++){
    int L = (t*2 + s) * 8;
    int kb = L & 15, nl = (L >> 4) & 63, h = L >> 10;
    int jt = tile * 4 + (nl >> 4);
    if (jt < NJT){
      *(uint4*)(Qt + ((((long)bs*BH + h)*NJT + jt)*16 + (nl&15))*16 + kb)
          = *(const uint4*)&stC[nl][h*16 + kb];
      long kbase = ((long)bs*BH + h) * KVSZ;
      if (jt < 44){
        s16x4 dlo = *(const s16x4*)&stD[nl][h*16 + kb];
        s16x4 dhi = *(const s16x4*)&stD[nl][h*16 + kb + 4];
        long off = kbase + (jt>>1)*512 + (nl&15)*32 + (jt&1)*4;
        *(s16x4*)(Ktp + off + (kb>>2)*8)     = dlo;
        *(s16x4*)(Ktp + off + (kb>>2)*8 + 8) = dhi;
      } else {
        *(uint4*)(Ktp + kbase + KVTAIL + (nl&15)*16 + kb)
            = *(const uint4*)&stD[nl][h*16 + kb];
      }
    }
  }
}

// ---------------------------------------------------------------------------
// Kernel 2: merged attention. 128-thread blocks, grid (bs, 113). unit = yb*2+w:
//  unit in [0,45):   GAT — wave = 16-row tile rt = unit (no LDS, no barriers)
//  unit in [45,225): MHA — u = unit-45, h = u/45, rt = u%45 (h-major adjacency)
__global__ __launch_bounds__(128) void k_attn(
    const float* __restrict__ Wh1, const float2* __restrict__ EwP,
    const unsigned* __restrict__ mask, const bf16* __restrict__ WhS,
    const bf16* __restrict__ Qt, const bf16* __restrict__ Ktp,
    const bf16* __restrict__ Vtp,
    bf16* __restrict__ out1, bf16* __restrict__ o)
{
#if !HAVE_MFMA16K
  __shared__ short pw[2][16][48];
#endif
  int bs = blockIdx.x, yb = blockIdx.y;
  int t = threadIdx.x, w = t >> 6, lane = t & 63, quad = lane >> 4, l15 = lane & 15;
  int unit = yb * 2 + w;
  long sb = (long)bs * BN;

  if (unit < 45){
    // ======================= GAT path (factorized exp) =======================
    int rt = unit;
    int i = rt * 16 + l15;
    int ic = i < BN ? i : BN - 1;
    float e1 = Wh1[sb + ic];
    float Aa = __expf(e1), Cc = __expf(0.2f * e1);
    float invA = frcp(Aa);               // cond: e1+w2>0  <=>  exp(w2) > 1/exp(e1)
    const unsigned* mrow = mask + (long)ic * NCH;
    const float2* ew = EwP + sb;

    float sl = 0.f;
    f32x4 acc0 = {0,0,0,0}, acc1 = {0,0,0,0}, acc2 = {0,0,0,0}, acc3 = {0,0,0,0};
    for (int ch = 0; ch < NCH; ch++){
      int j0 = ch * 32 + quad * 8;
      unsigned m8 = (mrow[ch] >> (quad * 8)) & 0xFFu;
      const float4* ef = (const float4*)(ew + j0);  // OOB tail: finite, masked
      float4 q0 = ef[0], q1 = ef[1], q2 = ef[2], q3 = ef[3];
      float Bv[8] = {q0.x, q0.z, q1.x, q1.z, q2.x, q2.z, q3.x, q3.z};
      float Dv[8] = {q0.y, q0.w, q1.y, q1.w, q2.y, q2.w, q3.y, q3.w};
      float p[8];
#pragma unroll
      for (int jj = 0; jj < 8; jj++){
        bool cond = Bv[jj] > invA;
        float f = cond ? Bv[jj] : Dv[jj];
        float g = cond ? Aa : Cc;
        float pp = ((m8 >> jj) & 1u) ? f * g : 0.f;
        sl += pp;
        p[jj] = pp;
      }
      union { unsigned u[4]; short8 v; } A;
      A.u[0] = packbf(p[0], p[1]); A.u[1] = packbf(p[2], p[3]);
      A.u[2] = packbf(p[4], p[5]); A.u[3] = packbf(p[6], p[7]);
      const bf16* wbp = WhS + ((long)bs*NCH + ch)*2048 + quad * 8;
      acc0 = MFMA16(A.v, *(const short8*)(wbp + ( 0 + l15) * 32), acc0);
      acc1 = MFMA16(A.v, *(const short8*)(wbp + (16 + l15) * 32), acc1);
      acc2 = MFMA16(A.v, *(const short8*)(wbp + (32 + l15) * 32), acc2);
      acc3 = MFMA16(A.v, *(const short8*)(wbp + (48 + l15) * 32), acc3);
    }
    sl += __shfl_xor(sl, 16);
    sl += __shfl_xor(sl, 32);
    float inv[4];
#pragma unroll
    for (int reg = 0; reg < 4; reg++){
      int srcl = quad * 4 + reg;
      float s = __int_as_float(__builtin_amdgcn_ds_bpermute(srcl << 2, __float_as_int(sl)));
      inv[reg] = 1.0f / s;
    }
    const f32x4* accs[4] = {&acc0, &acc1, &acc2, &acc3};
#pragma unroll
    for (int nt = 0; nt < 4; nt++){
#pragma unroll
      for (int reg = 0; reg < 4; reg++){
        int gi = rt * 16 + quad * 4 + reg;
        if (gi < BN){
          float val = (*accs[nt])[reg] * inv[reg];
          val = (val > 0.f) ? val : (__expf(val) - 1.f);   // ELU
          out1[(sb + gi) * BD + nt*16 + l15] = f2b(val);
        }
      }
    }
    return;
  }
  if (unit >= 225) return;

  // ======================= MHA path (paired jt, dual accumulators) =======================
  int u = unit - 45;
  int h = u / 45, rt = u - h * 45;
  const bf16* Qh = Qt  + ((long)bs*BH + h) * (long)KVSZ;
  const bf16* Kh = Ktp + ((long)bs*BH + h) * (long)KVSZ;
  const bf16* Vh = Vtp + ((long)bs*BH + h) * (long)KVSZ;

#if HAVE_MFMA16K
  s16x4 bq16 = *(const s16x4*)(Qh + rt*256 + l15*16 + quad*4);  // B: Q[q=l15][k]
  f32x4 oA = {0,0,0,0}, oB = {0,0,0,0};
  float psA = 0.f, psB = 0.f;
#pragma unroll 2
  for (int jp = 0; jp < NJP; jp++){
    short8 akp = *(const short8*)(Kh + jp*512 + l15*32 + quad*8);   // [jt0 k4 | jt1 k4]
    short8 bvp = *(const short8*)(Vh + jp*512 + lane*8);            // [jt0 v4 | jt1 v4]
    s16x4 ak0 = {akp[0], akp[1], akp[2], akp[3]};
    s16x4 ak1 = {akp[4], akp[5], akp[6], akp[7]};
    f32x4 c0 = mfma16k(ak0, bq16, ((f32x4){0,0,0,0}));   // S^T (log2 domain)
    f32x4 c1 = mfma16k(ak1, bq16, ((f32x4){0,0,0,0}));
    float p0[4], p1[4];
#pragma unroll
    for (int reg = 0; reg < 4; reg++){
      float a = fexp2(c0[reg]); psA += a; p0[reg] = a;
      float b = fexp2(c1[reg]); psB += b; p1[reg] = b;
    }
    union { unsigned u2[2]; s16x4 v; } A0, A1;
    A0.u2[0] = packbf(p0[0], p0[1]); A0.u2[1] = packbf(p0[2], p0[3]);
    A1.u2[0] = packbf(p1[0], p1[1]); A1.u2[1] = packbf(p1[2], p1[3]);
    s16x4 bv0 = {bvp[0], bvp[1], bvp[2], bvp[3]};
    s16x4 bv1 = {bvp[4], bvp[5], bvp[6], bvp[7]};
    oA = mfma16k(A0.v, bv0, oA);
    oB = mfma16k(A1.v, bv1, oB);
  }
  { // tail jt = 44: zero j >= 716 (quad 3 rows of S^T)
    s16x4 ak = *(const s16x4*)(Kh + KVTAIL + l15*16 + quad*4);
    f32x4 c = mfma16k(ak, bq16, ((f32x4){0,0,0,0}));
    float p[4];
#pragma unroll
    for (int reg = 0; reg < 4; reg++){
      float pp = (quad == 3) ? 0.f : fexp2(c[reg]);
      psA += pp;
      p[reg] = pp;
    }
    union { unsigned u2[2]; s16x4 v; } A;
    A.u2[0] = packbf(p[0], p[1]); A.u2[1] = packbf(p[2], p[3]);
    s16x4 bv = *(const s16x4*)(Vh + KVTAIL + lane*4);
    oA = mfma16k(A.v, bv, oA);
  }
  f32x4 oacc = oA + oB;
  float psum = psA + psB;
#else
  short8 aq = {0,0,0,0,0,0,0,0};
  if (quad < 2) aq = *(const short8*)(Qh + rt*256 + l15*16 + quad*8);
  f32x4 oacc = {0,0,0,0};
  float psum = 0.f;
  for (int ch = 0; ch < NCH; ch++){
#pragma unroll
    for (int tt = 0; tt < 2; tt++){
      int jt = 2*ch + tt;
      if (jt < NJT){
        short8 ak = {0,0,0,0,0,0,0,0};
        if (quad < 2){
          const bf16* kp = (jt < 44) ? Kh + (jt>>1)*512 + l15*32 + (jt&1)*4
                                     : Kh + KVTAIL + l15*16;
          int kstep = (jt < 44) ? 8 : 4;
          s16x4 klo = *(const s16x4*)(kp + (2*quad)   * kstep);
          s16x4 khi = *(const s16x4*)(kp + (2*quad+1) * kstep);
          ak[0]=klo[0]; ak[1]=klo[1]; ak[2]=klo[2]; ak[3]=klo[3];
          ak[4]=khi[0]; ak[5]=khi[1]; ak[6]=khi[2]; ak[7]=khi[3];
        }
        f32x4 c = MFMA16(ak, aq, ((f32x4){0,0,0,0}));
        bool inval = (jt == NJT-1) && (quad == 3);
#pragma unroll
        for (int reg = 0; reg < 4; reg++){
          float pp = fexp2(c[reg]);
          pp = inval ? 0.f : pp;
          psum += pp;
          pw[w][l15][tt*16 + quad*4 + reg] = (short)((__float_as_uint(pp) + 0x8000u) >> 16);
        }
      } else {
#pragma unroll
        for (int reg = 0; reg < 4; reg++) pw[w][l15][tt*16 + quad*4 + reg] = 0;
      }
    }
    short8 ap = *(const short8*)&pw[w][l15][quad*8];
    int jB = 2*ch + (quad >> 1);
    s16x4 v0 = {0,0,0,0}, v1 = {0,0,0,0};
    if (jB < NJT){
      int L0 = ((quad&1)*2    )*16 + l15;
      int L1 = ((quad&1)*2 + 1)*16 + l15;
      const bf16* vp0 = (jB < 44) ? Vh + (jB>>1)*512 + L0*8 + (jB&1)*4 : Vh + KVTAIL + L0*4;
      const bf16* vp1 = (jB < 44) ? Vh + (jB>>1)*512 + L1*8 + (jB&1)*4 : Vh + KVTAIL + L1*4;
      v0 = *(const s16x4*)vp0;
      v1 = *(const s16x4*)vp1;
    }
    short8 bv8; bv8[0]=v0[0]; bv8[1]=v0[1]; bv8[2]=v0[2]; bv8[3]=v0[3];
    bv8[4]=v1[0]; bv8[5]=v1[1]; bv8[6]=v1[2]; bv8[7]=v1[3];
    oacc = MFMA16(ap, bv8, oacc);
  }
#endif

  psum += __shfl_xor(psum, 16);
  psum += __shfl_xor(psum, 32);
#pragma unroll
  for (int reg = 0; reg < 4; reg++){
    int srcl = quad * 4 + reg;
    float s = __int_as_float(__builtin_amdgcn_ds_bpermute(srcl << 2, __float_as_int(psum)));
    int grow = rt * 16 + srcl;
    if (grow < BN)
      o[(sb + grow) * BD + h * BDH + l15] = f2b(oacc[reg] / s);
  }
}

// ---------------------------------------------------------------------------
// Kernel 3: MFMA epilogue: out = [out1|o] @ WF^T + bfuse.
__global__ __launch_bounds__(256) void k_final(
    const bf16* __restrict__ out1, const bf16* __restrict__ o,
    const bf16* __restrict__ WF, const float* __restrict__ bfuse,
    float* __restrict__ out)
{
  int t = threadIdx.x, w = t >> 6, lane = t & 63, quad = lane >> 4, l15 = lane & 15;
  long r0 = (long)blockIdx.x * 64;
  long row = r0 + w * 16 + l15;
  const bf16* o1r = out1 + row * BD;
  const bf16* oor = o    + row * BD;
  f32x4 acc[4];
#pragma unroll
  for (int i2 = 0; i2 < 4; i2++) acc[i2] = (f32x4){0,0,0,0};
#pragma unroll
  for (int kc = 0; kc < 2; kc++){
    int k0 = kc * 32 + quad * 8;
    short8 a1 = *(const short8*)(o1r + k0);
    short8 a2 = *(const short8*)(oor + k0);
#pragma unroll
    for (int nt = 0; nt < 4; nt++){
      acc[nt] = MFMA16(a1, *(const short8*)(WF + (nt*16 + l15) * 128 + k0), acc[nt]);
      acc[nt] = MFMA16(a2, *(const short8*)(WF + (nt*16 + l15) * 128 + 64 + k0), acc[nt]);
    }
  }
#pragma unroll
  for (int nt = 0; nt < 4; nt++){
    float bf = bfuse[nt*16 + l15];
#pragma unroll
    for (int reg = 0; reg < 4; reg++)
      out[(r0 + w*16 + quad*4 + reg) * BD + nt*16 + l15] = acc[nt][reg] + bf;
  }
}

// ---------------------------------------------------------------------------
extern "C" void kernel_launch(void* const* d_in, const int* in_sizes, int n_in,
                              void* d_out, int out_size, void* d_ws, size_t ws_size,
                              hipStream_t stream){
  const float* inp    = (const float*)d_in[0];
  const int*   adj    = (const int*)  d_in[1];
  const int*   ind    = (const int*)  d_in[2];
  const int*   outd   = (const int*)  d_in[3];
  const float* in_emb = (const float*)d_in[4];
  const float* out_emb= (const float*)d_in[5];
  const float* W      = (const float*)d_in[6];
  const float* a1     = (const float*)d_in[7];
  const float* a2     = (const float*)d_in[8];
  const float* Wq     = (const float*)d_in[9];
  const float* bq     = (const float*)d_in[10];
  const float* Wk     = (const float*)d_in[11];
  const float* bk     = (const float*)d_in[12];
  const float* Wv     = (const float*)d_in[13];
  const float* bv     = (const float*)d_in[14];
  const float* Wo     = (const float*)d_in[15];
  const float* bo     = (const float*)d_in[16];
  const float* Wp     = (const float*)d_in[17];
  const float* bp     = (const float*)d_in[18];

  const long PER  = (long)BBS * BN * BD;             // 2,199,552
  const long WHS  = (long)BBS * NCH * 64 * 32;       // 2,260,992
  const long QTS  = (long)BBS * BH * KVSZ;           // 2,211,840
  bf16* WhSb  = (bf16*)d_ws;
  bf16* Vtpb  = WhSb + WHS;
  bf16* Qtb   = Vtpb + QTS;
  bf16* Ktpb  = Qtb  + QTS;
  bf16* o1B   = Ktpb + QTS;
  bf16* oB    = o1B + PER;            // dedicated (GAT/MHA blocks run concurrently)
  bf16* WBb   = oB  + PER;            // 256*64
  bf16* WFb   = WBb + 256 * BD;       // 64*128
  unsigned* maskb = (unsigned*)(WFb + BD * 128);     // 716*23 words (16B-aligned)
  float2* EwPb = (float2*)(maskb + BN * NCH);        // BBS*BN pairs + 32 pad
  float* fws  = (float*)(EwPb + (long)BBS * BN + 32);
  float* Wh1  = fws;
  float* bfuse= Wh1 + (long)BBS * BN + 64;
  // total ~= 27.3 MiB (ws_size = 256 MiB per harness poison-fill size)

  hipLaunchKernelGGL(k_prep, dim3(102), dim3(256), 0, stream,
                     adj, W, Wq, Wk, Wv, Wo, bo, Wp, bp,
                     maskb, WBb, WFb, bfuse);
  hipLaunchKernelGGL(k_proj, dim3(BBS, 12), dim3(256), 0, stream,
                     inp, ind, outd, in_emb, out_emb, a1, a2, WBb, bq, bk, bv,
                     WhSb, Wh1, EwPb, Qtb, Ktpb, Vtpb);
  hipLaunchKernelGGL(k_attn, dim3(BBS, 113), dim3(128), 0, stream,
                     Wh1, EwPb, maskb, WhSb, Qtb, Ktpb, Vtpb, o1B, oB);
  hipLaunchKernelGGL(k_final, dim3(537), dim3(256), 0, stream,
                     o1B, oB, WFb, bfuse, (float*)d_out);
}